// Round 1
// baseline (494.375 us; speedup 1.0000x reference)
//
#include <hip/hip_runtime.h>
#include <hip/hip_bf16.h>

#define B_ROWS 16384
#define D_COLS 4096
#define BLOCK 256
#define WAVES_PER_BLOCK (BLOCK / 64)
// One wave per row: 4096 float/row = 1024 float4 / 64 lanes = 16 float4 per lane per input.
#define F4_PER_LANE (D_COLS / 4 / 64)

typedef float f32x4 __attribute__((ext_vector_type(4)));

__global__ __launch_bounds__(BLOCK, 4) void cos_sim_kernel(
    const float* __restrict__ x1,
    const float* __restrict__ x2,
    float* __restrict__ out)
{
    const int wave = threadIdx.x >> 6;
    const int lane = threadIdx.x & 63;
    const int row  = blockIdx.x * WAVES_PER_BLOCK + wave;
    const size_t base = (size_t)row * D_COLS;

    const f32x4* __restrict__ r1 = reinterpret_cast<const f32x4*>(x1 + base);
    const f32x4* __restrict__ r2 = reinterpret_cast<const f32x4*>(x2 + base);

    float dot = 0.0f, sx = 0.0f, sy = 0.0f;

    // Plain (cache-allocating) loads: the previous version used
    // __builtin_nontemporal_load; nt buys nothing for a single-touch stream
    // and is suspected of degrading read throughput vs the ~6.7 TB/s the
    // harness's own fill kernels reach. Partial unroll 4 -> 8 float4 loads
    // in flight per wave, plenty of MLP at 4+ waves/SIMD.
#pragma unroll 4
    for (int it = 0; it < F4_PER_LANE; ++it) {
        f32x4 a = r1[lane + it * 64];
        f32x4 b = r2[lane + it * 64];
        dot += a.x * b.x + a.y * b.y + a.z * b.z + a.w * b.w;
        sx  += a.x * a.x + a.y * a.y + a.z * a.z + a.w * a.w;
        sy  += b.x * b.x + b.y * b.y + b.z * b.z + b.w * b.w;
    }

    // Wave-64 butterfly reduction — no LDS, no barrier.
#pragma unroll
    for (int off = 32; off > 0; off >>= 1) {
        dot += __shfl_down(dot, off, 64);
        sx  += __shfl_down(sx,  off, 64);
        sy  += __shfl_down(sy,  off, 64);
    }

    if (lane == 0) {
        out[row] = 0.5f * dot / (sqrtf(sx) * sqrtf(sy));
    }
}

extern "C" void kernel_launch(void* const* d_in, const int* in_sizes, int n_in,
                              void* d_out, int out_size, void* d_ws, size_t ws_size,
                              hipStream_t stream) {
    const float* x1 = (const float*)d_in[0];
    const float* x2 = (const float*)d_in[1];
    float* out = (float*)d_out;

    cos_sim_kernel<<<B_ROWS / WAVES_PER_BLOCK, BLOCK, 0, stream>>>(x1, x2, out);
}

// Round 2
// 472.592 us; speedup vs baseline: 1.0461x; 1.0461x over previous
//
#include <hip/hip_runtime.h>
#include <hip/hip_bf16.h>

#define B_ROWS 16384
#define D_COLS 4096
#define BLOCK 256
#define WAVES_PER_BLOCK (BLOCK / 64)
// One wave per row: 4096 float/row = 1024 float4 / 64 lanes = 16 float4 per lane per input.
#define F4_PER_LANE (D_COLS / 4 / 64)

typedef float f32x4 __attribute__((ext_vector_type(4)));

__global__ __launch_bounds__(BLOCK, 4) void cos_sim_kernel(
    const float* __restrict__ x1,
    const float* __restrict__ x2,
    float* __restrict__ out)
{
    const int wave = threadIdx.x >> 6;
    const int lane = threadIdx.x & 63;
    const int row  = blockIdx.x * WAVES_PER_BLOCK + wave;
    const size_t base = (size_t)row * D_COLS;

    // nt (no-allocate) loads are REQUIRED here: the harness's 1 GiB poison
    // fill leaves L2/L3 dirty right before this kernel; cache-allocating
    // reads trigger an eviction storm (round 1: removing nt cost +28.5 us).
    const f32x4* __restrict__ r1 = reinterpret_cast<const f32x4*>(x1 + base) + lane;
    const f32x4* __restrict__ r2 = reinterpret_cast<const f32x4*>(x2 + base) + lane;

    float dot = 0.0f, sx = 0.0f, sy = 0.0f;

    // Unroll 8: 16 float4 nt-loads in flight per wave (~64 VGPRs of data).
    // nt loads always pay full HBM latency, so deeper MLP is the lever;
    // still within the 128-VGPR cap of __launch_bounds__(256,4).
#pragma unroll 8
    for (int it = 0; it < F4_PER_LANE; ++it) {
        f32x4 a = __builtin_nontemporal_load(&r1[it * 64]);
        f32x4 b = __builtin_nontemporal_load(&r2[it * 64]);
        dot += a.x * b.x + a.y * b.y + a.z * b.z + a.w * b.w;
        sx  += a.x * a.x + a.y * a.y + a.z * a.z + a.w * a.w;
        sy  += b.x * b.x + b.y * b.y + b.z * b.z + b.w * b.w;
    }

    // Wave-64 butterfly reduction — no LDS, no barrier.
#pragma unroll
    for (int off = 32; off > 0; off >>= 1) {
        dot += __shfl_down(dot, off, 64);
        sx  += __shfl_down(sx,  off, 64);
        sy  += __shfl_down(sy,  off, 64);
    }

    if (lane == 0) {
        out[row] = 0.5f * dot / (sqrtf(sx) * sqrtf(sy));
    }
}

extern "C" void kernel_launch(void* const* d_in, const int* in_sizes, int n_in,
                              void* d_out, int out_size, void* d_ws, size_t ws_size,
                              hipStream_t stream) {
    const float* x1 = (const float*)d_in[0];
    const float* x2 = (const float*)d_in[1];
    float* out = (float*)d_out;

    cos_sim_kernel<<<B_ROWS / WAVES_PER_BLOCK, BLOCK, 0, stream>>>(x1, x2, out);
}

// Round 3
// 465.828 us; speedup vs baseline: 1.0613x; 1.0145x over previous
//
#include <hip/hip_runtime.h>
#include <hip/hip_bf16.h>

#define B_ROWS 16384
#define D_COLS 4096
#define BLOCK 256
#define WAVES_PER_BLOCK (BLOCK / 64)
// One wave per row: 4096 float/row = 1024 float4 / 64 lanes = 16 float4 per lane per input.
#define F4_PER_LANE (D_COLS / 4 / 64)

typedef float f32x4 __attribute__((ext_vector_type(4)));

// launch_bounds (256, 8): 8 waves/EU = 32 waves/CU (hardware max), double the
// previous (256, 4). Per-wave MLP is already sufficient (round 2: unroll 8 was
// neutral); the lever is outstanding nt-requests per CU, which scales with
// resident waves. Kernel fits in <64 VGPR at unroll 4, so no spill risk.
__global__ __launch_bounds__(BLOCK, 8) void cos_sim_kernel(
    const float* __restrict__ x1,
    const float* __restrict__ x2,
    float* __restrict__ out)
{
    const int wave = threadIdx.x >> 6;
    const int lane = threadIdx.x & 63;
    const int row  = blockIdx.x * WAVES_PER_BLOCK + wave;
    const size_t base = (size_t)row * D_COLS;

    // nt (no-allocate) loads are REQUIRED here: the harness's 1 GiB poison
    // fill leaves L2/L3 dirty right before this kernel; cache-allocating
    // reads trigger an eviction storm (round 1: removing nt cost +28.5 us).
    const f32x4* __restrict__ r1 = reinterpret_cast<const f32x4*>(x1 + base) + lane;
    const f32x4* __restrict__ r2 = reinterpret_cast<const f32x4*>(x2 + base) + lane;

    float dot = 0.0f, sx = 0.0f, sy = 0.0f;

    // Unroll 4 (known-good): 8 float4 nt-loads in flight per wave.
#pragma unroll 4
    for (int it = 0; it < F4_PER_LANE; ++it) {
        f32x4 a = __builtin_nontemporal_load(&r1[it * 64]);
        f32x4 b = __builtin_nontemporal_load(&r2[it * 64]);
        dot += a.x * b.x + a.y * b.y + a.z * b.z + a.w * b.w;
        sx  += a.x * a.x + a.y * a.y + a.z * a.z + a.w * a.w;
        sy  += b.x * b.x + b.y * b.y + b.z * b.z + b.w * b.w;
    }

    // Wave-64 butterfly reduction — no LDS, no barrier.
#pragma unroll
    for (int off = 32; off > 0; off >>= 1) {
        dot += __shfl_down(dot, off, 64);
        sx  += __shfl_down(sx,  off, 64);
        sy  += __shfl_down(sy,  off, 64);
    }

    if (lane == 0) {
        out[row] = 0.5f * dot / (sqrtf(sx) * sqrtf(sy));
    }
}

extern "C" void kernel_launch(void* const* d_in, const int* in_sizes, int n_in,
                              void* d_out, int out_size, void* d_ws, size_t ws_size,
                              hipStream_t stream) {
    const float* x1 = (const float*)d_in[0];
    const float* x2 = (const float*)d_in[1];
    float* out = (float*)d_out;

    cos_sim_kernel<<<B_ROWS / WAVES_PER_BLOCK, BLOCK, 0, stream>>>(x1, x2, out);
}